// Round 1
// 422.333 us; speedup vs baseline: 1.0032x; 1.0032x over previous
//
#include <hip/hip_runtime.h>
#include <cfloat>
#include <stdint.h>

// Problem constants
#define NROWS   32768
#define NCODES  8192
#define KDIM    256
#define QOUT_OFFSET (NROWS * KDIM)

// Main-kernel tiling
#define BM      64              // rows per block
#define BN      256             // codes per block-tile (4 waves x 64)
#define NQ      4               // codebook quarters
#define CODES_Q (NCODES / NQ)   // 2048
#define NKC     (KDIM / 32)     // 8
#define NIT     (CODES_Q / BN * NKC)   // 8 ct * 8 kc = 64
#define THREADS 256             // 4 waves

// Fragment-order panel geometry (per 128-code panel)
#define BPAN 8192               // 128 codes * 32 k * 2 B, one split
#define BBUF (2 * BPAN)         // hi+lo 16384
#define ALDS_SPLIT 32768        // 64 rows * 256 k * 2 B per split
// LDS: 2 * 32768 = 65536 B -> 2 blocks/CU

typedef __bf16 bf16x4 __attribute__((ext_vector_type(4)));
typedef __bf16 bf16x8 __attribute__((ext_vector_type(8)));
typedef float  f32x4  __attribute__((ext_vector_type(4)));

// ---------------------------------------------------------------------------
// K1: codebook -> hi/lo bf16 panels in MFMA-fragment order, + cnorm.
// Panel p = (code>>7)*8 + kc. Within panel: tile j=(code&127)>>4,
// frag-lane = ((kl>>3)<<4) | (code&15), slot byte = (j*64+lane)*16 + (kl&7)*2.
// ---------------------------------------------------------------------------
__global__ void vq_panel_kernel(const float* __restrict__ cb,
                                char* __restrict__ cbP,
                                float* __restrict__ cnorm) {
    const int t    = threadIdx.x;
    const int row  = t >> 2;
    const int seg  = t & 3;
    const int code = blockIdx.x * 64 + row;
    const int cl   = code & 127;
    const int pt   = code >> 7;
    const float4* cb4 = (const float4*)cb;

    float ssq = 0.f;
    #pragma unroll
    for (int i = 0; i < 16; ++i) {
        int f = seg * 16 + i;            // float4 index in row, 0..63
        float4 v = cb4[(size_t)code * 64 + f];
        int k   = f * 4;
        int kc  = k >> 5;
        int kl  = k & 31;
        int oct = kl >> 3;
        int rem = kl & 7;                // 0 or 4
        bf16x4 h, l;
        float xs[4] = {v.x, v.y, v.z, v.w};
        #pragma unroll
        for (int e = 0; e < 4; ++e) {
            __bf16 hh = (__bf16)xs[e];
            h[e] = hh;
            l[e] = (__bf16)(xs[e] - (float)hh);
            ssq  = fmaf(xs[e], xs[e], ssq);
        }
        int lanefrag = (oct << 4) | (cl & 15);
        char* base = cbP + ((size_t)(pt * NKC + kc)) * BBUF
                         + ((cl >> 4) * 64 + lanefrag) * 16 + rem * 2;
        *(bf16x4*)base          = h;
        *(bf16x4*)(base + BPAN) = l;
    }
    ssq += __shfl_xor(ssq, 1, 64);
    ssq += __shfl_xor(ssq, 2, 64);
    if (seg == 0) cnorm[code] = ssq;
}

// ---------------------------------------------------------------------------
// K2: split-bf16 MFMA distances + per-quarter argmin partials.
// Barrier-free K-loop. NEW this round:
//   * A fragments register-double-buffered (ds_reads for iter n+1 issued
//     before iter n's MFMA cluster -> no lgkmcnt stall in front of MFMAs)
//   * strength-reduced addressing: one base per iter for the 8 B loads
//     (j*1024 immediates) and one VGPR base for the 8 A ds_reads
//     (i*1024 / +32768 immediates)
//   * cnorm prefetched at kc==0 (used at kc==7)
//   * s_setprio(1) around the MFMA cluster (independent blocks, no
//     lockstep barrier -> scheduler has role diversity to exploit)
// ---------------------------------------------------------------------------
__global__ __launch_bounds__(THREADS, 2) void vq_main_kernel(
        const float* __restrict__ z, const char* __restrict__ cbP,
        const float* __restrict__ cnorm,
        float* __restrict__ partD, int* __restrict__ partI) {

    __shared__ __align__(16) char Alds[2 * ALDS_SPLIT];   // 65536 B

    const int t     = threadIdx.x;
    const int wave  = t >> 6;
    const int lane  = t & 63;
    const int l15   = lane & 15;
    const int q     = blockIdx.x >> 9;
    const int row0  = (blockIdx.x & 511) * BM;
    const int qcode = q * CODES_Q;
    const int qp16  = q * 16;              // global 128-code panel-group base
    const int wp    = wave >> 1;           // wave's panel sub-group
    const int bvoff = ((wave & 1) * 256 + lane) * 16;   // lane part of B addr

    const float4* z4 = (const float4*)z;

    f32x4 acc[4][4];
    float mv[16];
    int   mi[16];
    #pragma unroll
    for (int i = 0; i < 4; ++i)
        #pragma unroll
        for (int j = 0; j < 4; ++j)
            acc[i][j] = (f32x4){0.f, 0.f, 0.f, 0.f};
    #pragma unroll
    for (int s = 0; s < 16; ++s) { mv[s] = FLT_MAX; mi[s] = 0; }

    // ---- prologue: stage A (all 8 kc, hi+lo, fragment order) ----
    {
        const int arow = t >> 2;
        const int aseg = t & 3;
        #pragma unroll
        for (int p = 0; p < 8; ++p) {
            float4 f0 = z4[(size_t)(row0 + arow) * 64 + aseg * 16 + 2 * p];
            float4 f1 = z4[(size_t)(row0 + arow) * 64 + aseg * 16 + 2 * p + 1];
            float xs[8] = {f0.x, f0.y, f0.z, f0.w, f1.x, f1.y, f1.z, f1.w};
            bf16x8 hv, lv;
            #pragma unroll
            for (int e = 0; e < 8; ++e) {
                __bf16 hh = (__bf16)xs[e];
                hv[e] = hh;
                lv[e] = (__bf16)(xs[e] - (float)hh);
            }
            int kc  = aseg * 2 + (p >> 2);
            int oct = p & 3;
            int slot = ((kc * 4 + (arow >> 4)) * 64 + (oct << 4) + (arow & 15)) * 16;
            *(bf16x8*)(Alds + slot)              = hv;
            *(bf16x8*)(Alds + ALDS_SPLIT + slot) = lv;
        }
    }

    // ---- prologue: B fragments for iter 0 (ct=0, kc=0) ----
    bf16x8 B0h[4], B0l[4], B1h[4], B1l[4];
    {
        const char* pb  = cbP + ((size_t)(qp16 + wp) * 8) * BBUF + bvoff;
        const char* pbl = pb + BPAN;
        #pragma unroll
        for (int j = 0; j < 4; ++j) {
            B0h[j] = *(const bf16x8*)(pb  + j * 1024);
            B0l[j] = *(const bf16x8*)(pbl + j * 1024);
        }
    }

    __syncthreads();   // A ready; the ONLY barrier before the reduction

    // ---- prologue: A fragments for iter 0 (kc=0) ----
    bf16x8 A0h[4], A0l[4], A1h[4], A1l[4];
    {
        const char* ab = Alds + (lane << 4);
        #pragma unroll
        for (int i = 0; i < 4; ++i) {
            A0h[i] = *(const bf16x8*)(ab + i * 1024);
            A0l[i] = *(const bf16x8*)(ab + ALDS_SPLIT + i * 1024);
        }
    }

    float cnj[4];

#define VQ_BODY(N, CAH, CAL, NAH, NAL, CBH, CBL, NBH, NBL)                    \
    {                                                                         \
        const int ct = (N) >> 3, kc = (N) & 7;                                \
        const int np = (N) + 1;                                               \
        if (np < NIT) {                                                       \
            const int ct1 = np >> 3, kc1 = np & 7;                            \
            const char* pb  = cbP                                             \
                + ((size_t)((qp16 + ct1 * 2 + wp) * 8 + kc1)) * BBUF + bvoff; \
            const char* pbl = pb + BPAN;                                      \
            _Pragma("unroll")                                                 \
            for (int j = 0; j < 4; ++j) {                                     \
                NBH[j] = *(const bf16x8*)(pb  + j * 1024);                    \
                NBL[j] = *(const bf16x8*)(pbl + j * 1024);                    \
            }                                                                 \
        }                                                                     \
        {                                                                     \
            const int kcn = np & 7;                                           \
            const char* ab = Alds + (kcn << 12) + (lane << 4);                \
            _Pragma("unroll")                                                 \
            for (int i = 0; i < 4; ++i) {                                     \
                NAH[i] = *(const bf16x8*)(ab + i * 1024);                     \
                NAL[i] = *(const bf16x8*)(ab + ALDS_SPLIT + i * 1024);        \
            }                                                                 \
        }                                                                     \
        if (kc == 0) {                                                        \
            _Pragma("unroll")                                                 \
            for (int j = 0; j < 4; ++j)                                       \
                cnj[j] = cnorm[qcode + (ct * 16 + wave * 4 + j) * 16 + l15];  \
        }                                                                     \
        __builtin_amdgcn_s_setprio(1);                                        \
        _Pragma("unroll")                                                     \
        for (int i = 0; i < 4; ++i)                                           \
            _Pragma("unroll")                                                 \
            for (int j = 0; j < 4; ++j)                                       \
                acc[i][j] = __builtin_amdgcn_mfma_f32_16x16x32_bf16(          \
                                CAH[i], CBH[j], acc[i][j], 0, 0, 0);          \
        _Pragma("unroll")                                                     \
        for (int i = 0; i < 4; ++i)                                           \
            _Pragma("unroll")                                                 \
            for (int j = 0; j < 4; ++j)                                       \
                acc[i][j] = __builtin_amdgcn_mfma_f32_16x16x32_bf16(          \
                                CAH[i], CBL[j], acc[i][j], 0, 0, 0);          \
        _Pragma("unroll")                                                     \
        for (int i = 0; i < 4; ++i)                                           \
            _Pragma("unroll")                                                 \
            for (int j = 0; j < 4; ++j)                                       \
                acc[i][j] = __builtin_amdgcn_mfma_f32_16x16x32_bf16(          \
                                CAL[i], CBH[j], acc[i][j], 0, 0, 0);          \
        __builtin_amdgcn_s_setprio(0);                                        \
        if (kc == 7) {                                                        \
            _Pragma("unroll")                                                 \
            for (int j = 0; j < 4; ++j) {                                     \
                int code = qcode + (ct * 16 + wave * 4 + j) * 16 + l15;       \
                float cn = cnj[j];                                            \
                _Pragma("unroll")                                             \
                for (int i = 0; i < 4; ++i) {                                 \
                    _Pragma("unroll")                                         \
                    for (int r = 0; r < 4; ++r) {                             \
                        float d = fmaf(-2.f, acc[i][j][r], cn);               \
                        int s = i * 4 + r;                                    \
                        if (d < mv[s]) { mv[s] = d; mi[s] = code; }           \
                    }                                                         \
                    acc[i][j] = (f32x4){0.f, 0.f, 0.f, 0.f};                  \
                }                                                             \
            }                                                                 \
        }                                                                     \
    }

    for (int n = 0; n < NIT; n += 2) {
        VQ_BODY(n,     A0h, A0l, A1h, A1l, B0h, B0l, B1h, B1l)
        VQ_BODY(n + 1, A1h, A1l, A0h, A0l, B1h, B1l, B0h, B0l)
    }
#undef VQ_BODY

    // ---- reduction: 16-lane butterfly (codes), then cross-wave via LDS ----
    #pragma unroll
    for (int s = 0; s < 16; ++s) {
        #pragma unroll
        for (int m = 1; m <= 8; m <<= 1) {
            float ov = __shfl_xor(mv[s], m, 64);
            int   oi = __shfl_xor(mi[s], m, 64);
            if (ov < mv[s] || (ov == mv[s] && oi < mi[s])) { mv[s] = ov; mi[s] = oi; }
        }
    }
    __syncthreads();
    float* redV = (float*)Alds;                 // [4 wave][64 rows]
    int*   redI = (int*)(Alds + 4 * BM * 4);
    if (l15 == 0) {
        int qq = lane >> 4;
        #pragma unroll
        for (int i = 0; i < 4; ++i)
            #pragma unroll
            for (int r = 0; r < 4; ++r) {
                int ml = i * 16 + qq * 4 + r;
                redV[wave * BM + ml] = mv[i * 4 + r];
                redI[wave * BM + ml] = mi[i * 4 + r];
            }
    }
    __syncthreads();
    if (t < BM) {
        float bv = redV[t];
        int   bi = redI[t];
        #pragma unroll
        for (int w = 1; w < 4; ++w) {
            float v  = redV[w * BM + t];
            int   id = redI[w * BM + t];
            if (v < bv || (v == bv && id < bi)) { bv = v; bi = id; }
        }
        partD[(size_t)q * NROWS + row0 + t] = bv;
        partI[(size_t)q * NROWS + row0 + t] = bi;
    }
}

// ---------------------------------------------------------------------------
// K3: merge 4 quarter-partials per row -> final index (ascending q keeps
// numpy first-min tie-breaking).
// ---------------------------------------------------------------------------
__global__ void vq_merge_kernel(const float* __restrict__ partD,
                                const int* __restrict__ partI,
                                float* __restrict__ idx_out) {
    const int row = blockIdx.x * 256 + threadIdx.x;
    float bv = partD[row];
    int   bi = partI[row];
    #pragma unroll
    for (int q = 1; q < NQ; ++q) {
        float v  = partD[(size_t)q * NROWS + row];
        int   id = partI[(size_t)q * NROWS + row];
        if (v < bv || (v == bv && id < bi)) { bv = v; bi = id; }
    }
    idx_out[row] = (float)bi;
}

// ---------------------------------------------------------------------------
// K4: gather codebook rows into quantized output (bit-exact fp32).
// ---------------------------------------------------------------------------
__global__ void vq_gather_kernel(const float* __restrict__ cb,
                                 const float* __restrict__ idx_f,
                                 float* __restrict__ quant) {
    const int t   = threadIdx.x;
    const int row = blockIdx.x * 64 + (t >> 2);
    const int seg = t & 3;
    const int best = (int)idx_f[row];
    const float4* src = (const float4*)cb + (size_t)best * (KDIM / 4);
    float4* dst = (float4*)quant + (size_t)row * (KDIM / 4);
    #pragma unroll
    for (int i = 0; i < 16; ++i)
        dst[seg * 16 + i] = src[seg * 16 + i];
}

// ---------------------------------------------------------------------------
extern "C" void kernel_launch(void* const* d_in, const int* in_sizes, int n_in,
                              void* d_out, int out_size, void* d_ws, size_t ws_size,
                              hipStream_t stream) {
    const float* z  = (const float*)d_in[0];
    const float* cb = (const float*)d_in[1];
    float* quant   = (float*)d_out;
    float* idx_out = (float*)d_out + QOUT_OFFSET;
    float* cnorm   = (float*)d_ws;                 // 32 KB scratch
    char*  cbP     = (char*)d_out;                 // 8 MB panels in quant region
    float* partD   = (float*)((char*)d_out + 8 * 1024 * 1024);   // 512 KB
    int*   partI   = (int*)((char*)d_out + 8 * 1024 * 1024 + NQ * NROWS * 4);
    // panels+partials live inside the 32 MB quant region; K4 overwrites last

    vq_panel_kernel<<<NCODES / 64, 256, 0, stream>>>(cb, cbP, cnorm);
    vq_main_kernel<<<NQ * (NROWS / BM), THREADS, 0, stream>>>(z, cbP, cnorm, partD, partI);
    vq_merge_kernel<<<NROWS / 256, 256, 0, stream>>>(partD, partI, idx_out);
    vq_gather_kernel<<<NROWS / 64, 256, 0, stream>>>(cb, idx_out, quant);
}